// Round 11
// baseline (14.173 us; speedup 1.0000x reference)
//
#include <hip/hip_runtime.h>
#include <hip/hip_bf16.h>
#include <math.h>

#define HEADS 8
#define BATCH 4
#define SEQ 2048
#define CDIM 32
#define WINDOW 10

#define RPB 64                 // rows per block = 4 waves x 16-row MFMA tiles
#define VROWS 96               // V band rows staged (max PV row = 95)
#define VSTR 20                // u32 stride of packed V rows (16 + 4 pad)

typedef float f32x4 __attribute__((ext_vector_type(4)));
typedef short s16x8 __attribute__((ext_vector_type(8)));
#define MFMA16 __builtin_amdgcn_mfma_f32_16x16x32_bf16

union BF8 { s16x8 v; __hip_bfloat162 h[4]; };
union U32 { __hip_bfloat162 h; unsigned u; };
union U4  { unsigned u[4]; s16x8 v; };

// Per-wave 16-row tile; 48 key slots j <-> key t = sw-16+j; slot j valid for
// query q iff j in [q+6, q+26] and key not seq-masked.
// QK^T: C[key][q] = mfma(A=K direct-from-global, B=Q).
// PV (operand-swapped): O^T[ch][q] = mfma(A=V^T from LDS, B=P in-lane) with
// the shared slot->k bijection; P needs no cross-lane relayout.
// Softmax runs max-free in the log2 domain (scores bounded), so nothing
// serializes between QK^T and exp2 except the mask select.
__global__ __launch_bounds__(256) void lwin_attn_kernel(
    const float* __restrict__ Q, const float* __restrict__ K,
    const float* __restrict__ V, const float* __restrict__ G,
    const unsigned char* __restrict__ seqMask, float* __restrict__ out)
{
    __shared__ unsigned V_s[VROWS * VSTR];      // packed (ch c, ch c+16) bf16 pairs

    // XCD-aware swizzle (1024 blocks, 128 per XCD chunk)
    const int d = blockIdx.x;
    const int b = (d & 7) * 128 + (d >> 3);

    const int hn = b >> 5;                      // h*BATCH + n (32 blocks per hn)
    const int s0 = (b & 31) * RPB;
    const int n  = hn & 3;
    const int h  = hn >> 2;
    const int base_hn = hn * SEQ * CDIM;

    const int tid  = threadIdx.x;
    const int w    = tid >> 6;                  // wave = tile index 0..3
    const int lane = tid & 63;
    const int q    = lane & 15;                 // query-in-tile / MFMA N-col
    const int g    = lane >> 4;                 // lane group

    // ---- V staging: 384 tasks (i = 0..95, ch-quad o = 0..3), packed pairs ----
    {
        const int i = tid >> 2, o = tid & 3;
        const int t  = s0 - 16 + i;
        const int tc = min(max(t, 0), SEQ - 1);
        const float4 f0 = *(const float4*)&V[base_hn + tc * 32 + 4 * o];
        const float4 f1 = *(const float4*)&V[base_hn + tc * 32 + 16 + 4 * o];
        U32 w0, w1, w2, w3;
        w0.h = __float22bfloat162_rn(make_float2(f0.x, f1.x));
        w1.h = __float22bfloat162_rn(make_float2(f0.y, f1.y));
        w2.h = __float22bfloat162_rn(make_float2(f0.z, f1.z));
        w3.h = __float22bfloat162_rn(make_float2(f0.w, f1.w));
        *(uint4*)&V_s[i * VSTR + 4 * o] = make_uint4(w0.u, w1.u, w2.u, w3.u);
    }
    if (tid < 128) {
        const int task = tid + 256;
        const int i = task >> 2, o = task & 3;
        const int t  = s0 - 16 + i;
        const int tc = min(max(t, 0), SEQ - 1);
        const float4 f0 = *(const float4*)&V[base_hn + tc * 32 + 4 * o];
        const float4 f1 = *(const float4*)&V[base_hn + tc * 32 + 16 + 4 * o];
        U32 w0, w1, w2, w3;
        w0.h = __float22bfloat162_rn(make_float2(f0.x, f1.x));
        w1.h = __float22bfloat162_rn(make_float2(f0.y, f1.y));
        w2.h = __float22bfloat162_rn(make_float2(f0.z, f1.z));
        w3.h = __float22bfloat162_rn(make_float2(f0.w, f1.w));
        *(uint4*)&V_s[i * VSTR + 4 * o] = make_uint4(w0.u, w1.u, w2.u, w3.u);
    }

    const int sw = s0 + 16 * w;

    // ---- Q B-fragment (scaled, bf16) + G (prefetched for epilogue) ----
    const int rowq = hn * SEQ + sw + q;
    const float sc = 0.17677669529663687f * 1.4426950408889634f; // 1/sqrt(32)*log2e
    const float4 q0 = *(const float4*)&Q[rowq * 32 + 8 * g];
    const float4 q1 = *(const float4*)&Q[rowq * 32 + 8 * g + 4];
    BF8 bq;
    bq.h[0] = __float22bfloat162_rn(make_float2(q0.x * sc, q0.y * sc));
    bq.h[1] = __float22bfloat162_rn(make_float2(q0.z * sc, q0.w * sc));
    bq.h[2] = __float22bfloat162_rn(make_float2(q1.x * sc, q1.y * sc));
    bq.h[3] = __float22bfloat162_rn(make_float2(q1.z * sc, q1.w * sc));
    const float4 g0 = *(const float4*)&G[rowq * 32 + 4 * g];
    const float4 g1 = *(const float4*)&G[rowq * 32 + 16 + 4 * g];

    // ---- K A-fragments direct from global (per blk: wave covers one
    // contiguous 2 KB panel -> coalesced dwordx4) ----
    BF8 ak[3];
#pragma unroll
    for (int blk = 0; blk < 3; ++blk) {
        const int t  = sw - 16 + 16 * blk + q;
        const int tc = min(max(t, 0), SEQ - 1);
        const float4 k0 = *(const float4*)&K[base_hn + tc * 32 + 8 * g];
        const float4 k1 = *(const float4*)&K[base_hn + tc * 32 + 8 * g + 4];
        ak[blk].h[0] = __float22bfloat162_rn(make_float2(k0.x, k0.y));
        ak[blk].h[1] = __float22bfloat162_rn(make_float2(k0.z, k0.w));
        ak[blk].h[2] = __float22bfloat162_rn(make_float2(k1.x, k1.y));
        ak[blk].h[3] = __float22bfloat162_rn(make_float2(k1.z, k1.w));
    }

    // ---- per-wave seqMask ballot: bit l = band row 16w+l invalid ----
    unsigned long long mI;
    {
        const int t  = sw - 16 + lane;
        const int tc = min(max(t, 0), SEQ - 1);
        const bool inval = (t < 0) || (t >= SEQ) || (seqMask[n * SEQ + tc] != 0);
        mI = __ballot(inval);
    }
    const unsigned long long vm = (0x1FFFFFULL << (q + 6)) & ~mI;

    // ---- QK^T: 3 MFMAs; S[blk][r] = S[key slot 16blk+4g+r][q] ----
    f32x4 S[3];
#pragma unroll
    for (int blk = 0; blk < 3; ++blk)
        S[blk] = MFMA16(ak[blk].v, bq.v, (f32x4){0.f, 0.f, 0.f, 0.f}, 0, 0, 0);

    // ---- max-free masked exp2 + pack to bf16 (1/sum deferred) ----
    float sm = 0.f;
    unsigned pk[3][2];
#pragma unroll
    for (int blk = 0; blk < 3; ++blk) {
        float e[4];
#pragma unroll
        for (int r = 0; r < 4; ++r) {
            const int j = 16 * blk + 4 * g + r;
            const float x = ((vm >> j) & 1ULL) ? S[blk][r] : -1e30f;
            e[r] = __builtin_amdgcn_exp2f(x);
            sm += e[r];
        }
        U32 a, b2;
        a.h  = __float22bfloat162_rn(make_float2(e[0], e[1]));
        b2.h = __float22bfloat162_rn(make_float2(e[2], e[3]));
        pk[blk][0] = a.u;
        pk[blk][1] = b2.u;
    }
    sm += __shfl_xor(sm, 16);
    sm += __shfl_xor(sm, 32);

    __syncthreads();

    // ---- PV (swapped): O^T = A(V^T) * B(P) ----
    f32x4 O0 = {0.f, 0.f, 0.f, 0.f}, O1 = {0.f, 0.f, 0.f, 0.f};
    {   // sb = 0: slots 0..31
        const int R = 16 * w;
        unsigned r0[4], r1[4];
#pragma unroll
        for (int jj = 0; jj < 4; ++jj) {
            r0[jj] = V_s[(R + 4 * g + jj) * VSTR + q];
            r1[jj] = V_s[(R + 16 + 4 * g + jj) * VSTR + q];
        }
        U4 A0, A1v;
        A0.u[0]  = __builtin_amdgcn_perm(r0[1], r0[0], 0x05040100u);
        A0.u[1]  = __builtin_amdgcn_perm(r0[3], r0[2], 0x05040100u);
        A0.u[2]  = __builtin_amdgcn_perm(r1[1], r1[0], 0x05040100u);
        A0.u[3]  = __builtin_amdgcn_perm(r1[3], r1[2], 0x05040100u);
        A1v.u[0] = __builtin_amdgcn_perm(r0[1], r0[0], 0x07060302u);
        A1v.u[1] = __builtin_amdgcn_perm(r0[3], r0[2], 0x07060302u);
        A1v.u[2] = __builtin_amdgcn_perm(r1[1], r1[0], 0x07060302u);
        A1v.u[3] = __builtin_amdgcn_perm(r1[3], r1[2], 0x07060302u);
        U4 Bp;
        Bp.u[0] = pk[0][0]; Bp.u[1] = pk[0][1];
        Bp.u[2] = pk[1][0]; Bp.u[3] = pk[1][1];
        O0 = MFMA16(A0.v,  Bp.v, O0, 0, 0, 0);
        O1 = MFMA16(A1v.v, Bp.v, O1, 0, 0, 0);
    }
    {   // sb = 1: slots 32..47 live in k=0..3; k=4..7 are zero on both sides
        const int R = 16 * w + 32;
        unsigned r0[4];
#pragma unroll
        for (int jj = 0; jj < 4; ++jj)
            r0[jj] = V_s[(R + 4 * g + jj) * VSTR + q];       // max row 95
        U4 A0, A1v;
        A0.u[0]  = __builtin_amdgcn_perm(r0[1], r0[0], 0x05040100u);
        A0.u[1]  = __builtin_amdgcn_perm(r0[3], r0[2], 0x05040100u);
        A0.u[2]  = 0u; A0.u[3] = 0u;
        A1v.u[0] = __builtin_amdgcn_perm(r0[1], r0[0], 0x07060302u);
        A1v.u[1] = __builtin_amdgcn_perm(r0[3], r0[2], 0x07060302u);
        A1v.u[2] = 0u; A1v.u[3] = 0u;
        U4 Bp;
        Bp.u[0] = pk[2][0]; Bp.u[1] = pk[2][1];
        Bp.u[2] = 0u;       Bp.u[3] = 0u;
        O0 = MFMA16(A0.v,  Bp.v, O0, 0, 0, 0);
        O1 = MFMA16(A1v.v, Bp.v, O1, 0, 0, 0);
    }

    // ---- epilogue: lane(q,g) owns query sw+q, ch {4g..4g+3} u {16+4g..} ----
    const float invq = 1.0f / sm;
    float4 o0, o1;
    o0.x = O0[0] * invq * g0.x;  o0.y = O0[1] * invq * g0.y;
    o0.z = O0[2] * invq * g0.z;  o0.w = O0[3] * invq * g0.w;
    o1.x = O1[0] * invq * g1.x;  o1.y = O1[1] * invq * g1.y;
    o1.z = O1[2] * invq * g1.z;  o1.w = O1[3] * invq * g1.w;
    float* obase = &out[((n * SEQ + sw + q) * HEADS + h) * 32];
    *(float4*)&obase[4 * g]      = o0;
    *(float4*)&obase[16 + 4 * g] = o1;
}

extern "C" void kernel_launch(void* const* d_in, const int* in_sizes, int n_in,
                              void* d_out, int out_size, void* d_ws, size_t ws_size,
                              hipStream_t stream) {
    const float* Q = (const float*)d_in[0];
    const float* K = (const float*)d_in[1];
    const float* V = (const float*)d_in[2];
    const float* G = (const float*)d_in[3];
    const unsigned char* seqMask = (const unsigned char*)d_in[4];
    float* out = (float*)d_out;

    const int blocks = HEADS * BATCH * (SEQ / RPB);   // 1024
    lwin_attn_kernel<<<blocks, 256, 0, stream>>>(Q, K, V, G, seqMask, out);
}

// Round 12
// 12.941 us; speedup vs baseline: 1.0952x; 1.0952x over previous
//
#include <hip/hip_runtime.h>
#include <hip/hip_bf16.h>
#include <math.h>

#define HEADS 8
#define BATCH 4
#define SEQ 2048
#define CDIM 32
#define WINDOW 10

#define RPB 32                 // rows per block = 2 tiles x 16 rows; 2 waves/tile
#define BROWS 64               // K/V band rows staged: s0-16 .. s0+47
#define VSTR 20                // u32 stride of packed V rows (16 + 4 pad)

typedef float f32x4 __attribute__((ext_vector_type(4)));
typedef short s16x8 __attribute__((ext_vector_type(8)));
#define MFMA16 __builtin_amdgcn_mfma_f32_16x16x32_bf16

union BF8 { s16x8 v; __hip_bfloat162 h[4]; };
union U32 { __hip_bfloat162 h; unsigned u; };
union U4  { unsigned u[4]; s16x8 v; };

// Per-tile 16 rows; 48 key slots j <-> key t = sw-16+j; slot j valid for
// query q iff j in [q+6, q+26] and key not seq-masked.
// QK^T: C[key][q] = mfma(A=K from LDS, B=Q)  (both waves of a tile duplicate).
// PV (operand-swapped): O^T[ch][q] = mfma(A=V^T, B=P in-lane); each wave
// computes one 16-channel half (half = wave&1) -> 2x wave parallelism.
__global__ __launch_bounds__(256) void lwin_attn_kernel(
    const float* __restrict__ Q, const float* __restrict__ K,
    const float* __restrict__ V, const float* __restrict__ G,
    const unsigned char* __restrict__ seqMask, float* __restrict__ out)
{
    __shared__ short    K_s[BROWS * 32];        // bf16 K band, row-major [64][32]
    __shared__ unsigned V_s[BROWS * VSTR];      // packed (ch c, ch c+16) bf16 pairs

    // XCD-aware swizzle (2048 blocks, 256 per XCD chunk)
    const int d = blockIdx.x;
    const int b = (d & 7) * 256 + (d >> 3);

    const int hn = b >> 6;                      // h*BATCH + n (64 blocks per hn)
    const int s0 = (b & 63) * RPB;
    const int n  = hn & 3;
    const int h  = hn >> 2;
    const int base_hn = hn * SEQ * CDIM;

    const int tid  = threadIdx.x;
    const int wave = tid >> 6;
    const int tile = wave >> 1;                 // 0..1
    const int half = wave & 1;                  // output channel half for PV
    const int lane = tid & 63;
    const int q    = lane & 15;                 // query-in-tile / MFMA N-col
    const int g    = lane >> 4;                 // lane group

    // ---- stage K (task tid) and V (task tid) bands: i = tid>>2, o = tid&3 ----
    {
        const int i = tid >> 2, o = tid & 3;
        const int t  = s0 - 16 + i;
        const int tc = min(max(t, 0), SEQ - 1);
        // K: octet o -> channels 8o..8o+7, row-major bf16
        const float4 k0 = *(const float4*)&K[base_hn + tc * 32 + 8 * o];
        const float4 k1 = *(const float4*)&K[base_hn + tc * 32 + 8 * o + 4];
        // V: quad o -> packed (ch 4o+j, ch 16+4o+j) bf16 pairs
        const float4 f0 = *(const float4*)&V[base_hn + tc * 32 + 4 * o];
        const float4 f1 = *(const float4*)&V[base_hn + tc * 32 + 16 + 4 * o];
        BF8 uk;
        uk.h[0] = __float22bfloat162_rn(make_float2(k0.x, k0.y));
        uk.h[1] = __float22bfloat162_rn(make_float2(k0.z, k0.w));
        uk.h[2] = __float22bfloat162_rn(make_float2(k1.x, k1.y));
        uk.h[3] = __float22bfloat162_rn(make_float2(k1.z, k1.w));
        *(s16x8*)&K_s[i * 32 + 8 * o] = uk.v;
        U32 w0, w1, w2, w3;
        w0.h = __float22bfloat162_rn(make_float2(f0.x, f1.x));
        w1.h = __float22bfloat162_rn(make_float2(f0.y, f1.y));
        w2.h = __float22bfloat162_rn(make_float2(f0.z, f1.z));
        w3.h = __float22bfloat162_rn(make_float2(f0.w, f1.w));
        *(uint4*)&V_s[i * VSTR + 4 * o] = make_uint4(w0.u, w1.u, w2.u, w3.u);
    }

    const int sw   = s0 + 16 * tile;
    const int rowq = hn * SEQ + sw + q;

    // ---- Q B-fragment (scaled, bf16) + this wave's G half ----
    const float sc = 0.17677669529663687f * 1.4426950408889634f; // 1/sqrt(32)*log2e
    const float4 q0 = *(const float4*)&Q[rowq * 32 + 8 * g];
    const float4 q1 = *(const float4*)&Q[rowq * 32 + 8 * g + 4];
    BF8 bq;
    bq.h[0] = __float22bfloat162_rn(make_float2(q0.x * sc, q0.y * sc));
    bq.h[1] = __float22bfloat162_rn(make_float2(q0.z * sc, q0.w * sc));
    bq.h[2] = __float22bfloat162_rn(make_float2(q1.x * sc, q1.y * sc));
    bq.h[3] = __float22bfloat162_rn(make_float2(q1.z * sc, q1.w * sc));
    const float4 gh = *(const float4*)&G[rowq * 32 + 16 * half + 4 * g];

    // ---- per-wave seqMask ballot: bit l = tile band row l invalid ----
    unsigned long long mI;
    {
        const int t  = sw - 16 + lane;
        const int tc = min(max(t, 0), SEQ - 1);
        const bool inval = (t < 0) || (t >= SEQ) || (seqMask[n * SEQ + tc] != 0);
        mI = __ballot(inval);
    }
    const unsigned long long vm = (0x1FFFFFULL << (q + 6)) & ~mI;

    __syncthreads();

    // ---- QK^T: 3 MFMAs; S[blk][r] = S[key slot 16blk+4g+r][q] ----
    f32x4 S[3];
#pragma unroll
    for (int blk = 0; blk < 3; ++blk) {
        const s16x8 ak = *(const s16x8*)&K_s[(16 * tile + 16 * blk + q) * 32 + 8 * g];
        S[blk] = MFMA16(ak, bq.v, (f32x4){0.f, 0.f, 0.f, 0.f}, 0, 0, 0);
    }

    // ---- max-free masked exp2 + pack to bf16 (1/sum deferred) ----
    float sm = 0.f;
    unsigned pk[3][2];
#pragma unroll
    for (int blk = 0; blk < 3; ++blk) {
        float e[4];
#pragma unroll
        for (int r = 0; r < 4; ++r) {
            const int j = 16 * blk + 4 * g + r;
            const float x = ((vm >> j) & 1ULL) ? S[blk][r] : -1e30f;
            e[r] = __builtin_amdgcn_exp2f(x);
            sm += e[r];
        }
        U32 a, b2;
        a.h  = __float22bfloat162_rn(make_float2(e[0], e[1]));
        b2.h = __float22bfloat162_rn(make_float2(e[2], e[3]));
        pk[blk][0] = a.u;
        pk[blk][1] = b2.u;
    }
    sm += __shfl_xor(sm, 16);
    sm += __shfl_xor(sm, 32);

    // ---- PV (swapped, this wave's channel half only) ----
    const unsigned sel = half ? 0x07060302u : 0x05040100u;
    f32x4 O = {0.f, 0.f, 0.f, 0.f};
    {   // sb = 0: slots 0..31
        const int R = 16 * tile;
        unsigned r0[4], r1[4];
#pragma unroll
        for (int jj = 0; jj < 4; ++jj) {
            r0[jj] = V_s[(R + 4 * g + jj) * VSTR + q];
            r1[jj] = V_s[(R + 16 + 4 * g + jj) * VSTR + q];
        }
        U4 A;
        A.u[0] = __builtin_amdgcn_perm(r0[1], r0[0], sel);
        A.u[1] = __builtin_amdgcn_perm(r0[3], r0[2], sel);
        A.u[2] = __builtin_amdgcn_perm(r1[1], r1[0], sel);
        A.u[3] = __builtin_amdgcn_perm(r1[3], r1[2], sel);
        U4 Bp;
        Bp.u[0] = pk[0][0]; Bp.u[1] = pk[0][1];
        Bp.u[2] = pk[1][0]; Bp.u[3] = pk[1][1];
        O = MFMA16(A.v, Bp.v, O, 0, 0, 0);
    }
    {   // sb = 1: slots 32..47 in k=0..3; k=4..7 zero on both operands
        const int R = 16 * tile + 32;
        unsigned r0[4];
#pragma unroll
        for (int jj = 0; jj < 4; ++jj)
            r0[jj] = V_s[(R + 4 * g + jj) * VSTR + q];      // max row 63
        U4 A;
        A.u[0] = __builtin_amdgcn_perm(r0[1], r0[0], sel);
        A.u[1] = __builtin_amdgcn_perm(r0[3], r0[2], sel);
        A.u[2] = 0u; A.u[3] = 0u;
        U4 Bp;
        Bp.u[0] = pk[2][0]; Bp.u[1] = pk[2][1];
        Bp.u[2] = 0u;       Bp.u[3] = 0u;
        O = MFMA16(A.v, Bp.v, O, 0, 0, 0);
    }

    // ---- epilogue: lane(q,g) stores query sw+q, ch 16*half + 4g..4g+3 ----
    const float invq = 1.0f / sm;
    float4 o;
    o.x = O[0] * invq * gh.x;  o.y = O[1] * invq * gh.y;
    o.z = O[2] * invq * gh.z;  o.w = O[3] * invq * gh.w;
    *(float4*)&out[((n * SEQ + sw + q) * HEADS + h) * 32 + 16 * half + 4 * g] = o;
}

extern "C" void kernel_launch(void* const* d_in, const int* in_sizes, int n_in,
                              void* d_out, int out_size, void* d_ws, size_t ws_size,
                              hipStream_t stream) {
    const float* Q = (const float*)d_in[0];
    const float* K = (const float*)d_in[1];
    const float* V = (const float*)d_in[2];
    const float* G = (const float*)d_in[3];
    const unsigned char* seqMask = (const unsigned char*)d_in[4];
    float* out = (float*)d_out;

    const int blocks = HEADS * BATCH * (SEQ / RPB);   // 2048
    lwin_attn_kernel<<<blocks, 256, 0, stream>>>(Q, K, V, G, seqMask, out);
}